// Round 6
// baseline (608.736 us; speedup 1.0000x reference)
//
#include <hip/hip_runtime.h>
#include <hip/hip_bf16.h>
#include <hip/hip_fp16.h>

// Inputs/outputs are FP32 (verified R3/R6).
// R10 lesson: KV-in-regs OR weights-in-regs — never both (VGPR cap 256 -> spill).
// R11 lesson: redundant all-wave broadcast stages LOSE (4x LDS traffic > 3 barriers).
// R12 lesson: v_dot2 + fp16 LDS cut k_dec 450->335; VALUBusy 8% -> latency-bound.
// R13 lesson: dual-chain/block doubles per-CU throughput but wall time is set by
//   per-step CRITICAL PATH. R14 lesson: mega-wave0 segments + 2 barriers/step
//   cut 316->236us; implied clock ~1.1GHz (down-clocked at low occupancy) — the
//   cycle model was right, the 2.4GHz assumption wasn't.
// R15 (resubmit — prior round was an infra failure, "container failed twice"):
//   (a) Wo/Wcq/Wco columns in VGPRs (skip per-stage LDS weight gathers),
//   (b) y buffered in regs, single store after loop (no per-step vmcnt drain),
//   (c) A0 fused into C2; cross-attn drops wmax (fp32 P, normalize pre-fp16),
//   (d) encoder k_attn PV as float2 (v_pk_fma_f32).

constexpr int kB  = 128;
constexpr int kS  = 512;
constexpr int kT  = 64;
constexpr int kD  = 48;
constexpr int kFF = 128;
constexpr int kNH = 4;
constexpr int kHD = 12;

__device__ __forceinline__ void wsync(){
  __builtin_amdgcn_wave_barrier();
  asm volatile("" ::: "memory");
}

// ---- DPP wave64 reductions (VALU-speed) ----
template<int CTRL,int RM,int BM,bool BC>
__device__ __forceinline__ float dppmov(float x, float old){
  return __builtin_bit_cast(float, __builtin_amdgcn_update_dpp(
      __builtin_bit_cast(int, old), __builtin_bit_cast(int, x), CTRL, RM, BM, BC));
}
// sum across 64 lanes, result uniform in all lanes
__device__ __forceinline__ float wsum(float x){
  x += dppmov<0x111,0xf,0xf,true>(x, 0.f);   // row_shr:1
  x += dppmov<0x112,0xf,0xf,true>(x, 0.f);   // row_shr:2
  x += dppmov<0x114,0xf,0xf,true>(x, 0.f);   // row_shr:4
  x += dppmov<0x118,0xf,0xf,true>(x, 0.f);   // row_shr:8
  x += dppmov<0x142,0xa,0xf,true>(x, 0.f);   // row_bcast:15 -> rows 1,3
  x += dppmov<0x143,0xc,0xf,true>(x, 0.f);   // row_bcast:31 -> rows 2,3
  return __builtin_bit_cast(float, __builtin_amdgcn_readlane(__builtin_bit_cast(int, x), 63));
}
// sum within each 16-lane row; result valid at lane 15 of each row
__device__ __forceinline__ float rowsum16(float x){
  x += dppmov<0x111,0xf,0xf,true>(x, 0.f);
  x += dppmov<0x112,0xf,0xf,true>(x, 0.f);
  x += dppmov<0x114,0xf,0xf,true>(x, 0.f);
  x += dppmov<0x118,0xf,0xf,true>(x, 0.f);
  return x;
}

// pe[p, 2i] = sin(p * exp(-2i*ln(10000)/48)), pe[p, 2i+1] = cos(...)
__device__ __forceinline__ float pe_val(int p, int j){   // precise (table init)
  int i = j >> 1;
  float f = expf(-0.19188209108283716f * (float)(2*i));
  float a = (float)p * f;
  return (j & 1) ? cosf(a) : sinf(a);
}
__device__ __forceinline__ float pe_fast(int p, int j){  // encoder embed
  int i = j >> 1;
  float f = __expf(-0.19188209108283716f * (float)(2*i));
  float a = (float)p * f;
  return (j & 1) ? __cosf(a) : __sinf(a);
}

// ---- packed fp16 dot: d = a.x*b.x + a.y*b.y + c (v_dot2_f32_f16) ----
typedef _Float16 h2v __attribute__((ext_vector_type(2)));
union H2U { __half2 h; h2v v; };
__device__ __forceinline__ float fdot2(__half2 a, __half2 b, float c){
#if __has_builtin(__builtin_amdgcn_fdot2)
  H2U ua, ub; ua.h=a; ub.h=b;
  return __builtin_amdgcn_fdot2(ua.v, ub.v, c, false);
#else
  float2 fa=__half22float2(a), fb=__half22float2(b);
  return fmaf(fa.y, fb.y, fmaf(fa.x, fb.x, c));
#endif
}

// 48-dot, both operands fp16 (LDS or regs), 4 accumulator chains
__device__ __forceinline__ float dot48d(const __half2* x, const __half* w){
  const __half2* w2=(const __half2*)w;
  float a0=0.f,a1=0.f,a2=0.f,a3=0.f;
  #pragma unroll
  for(int c=0;c<6;c++){
    a0=fdot2(x[4*c+0],w2[4*c+0],a0);
    a1=fdot2(x[4*c+1],w2[4*c+1],a1);
    a2=fdot2(x[4*c+2],w2[4*c+2],a2);
    a3=fdot2(x[4*c+3],w2[4*c+3],a3);
  }
  return (a0+a1)+(a2+a3);
}
// 48-dot, x in LDS (broadcast), w in per-lane REGISTERS
__device__ __forceinline__ float dot48r(const __half2* x, const __half2* w){
  float a0=0.f,a1=0.f,a2=0.f,a3=0.f;
  #pragma unroll
  for(int c=0;c<6;c++){
    a0=fdot2(x[4*c+0],w[4*c+0],a0);
    a1=fdot2(x[4*c+1],w[4*c+1],a1);
    a2=fdot2(x[4*c+2],w[4*c+2],a2);
    a3=fdot2(x[4*c+3],w[4*c+3],a3);
  }
  return (a0+a1)+(a2+a3);
}
// 128-dot, 8 accumulator chains
__device__ __forceinline__ float dot128d(const __half2* x, const __half* w){
  const __half2* w2=(const __half2*)w;
  float a0=0.f,a1=0.f,a2=0.f,a3=0.f,a4=0.f,a5=0.f,a6=0.f,a7=0.f;
  #pragma unroll
  for(int c=0;c<8;c++){
    a0=fdot2(x[8*c+0],w2[8*c+0],a0);
    a1=fdot2(x[8*c+1],w2[8*c+1],a1);
    a2=fdot2(x[8*c+2],w2[8*c+2],a2);
    a3=fdot2(x[8*c+3],w2[8*c+3],a3);
    a4=fdot2(x[8*c+4],w2[8*c+4],a4);
    a5=fdot2(x[8*c+5],w2[8*c+5],a5);
    a6=fdot2(x[8*c+6],w2[8*c+6],a6);
    a7=fdot2(x[8*c+7],w2[8*c+7],a7);
  }
  return ((a0+a1)+(a2+a3))+((a4+a5)+(a6+a7));
}

// ---------------- K1: embed + PE -> X0 (fp32) ----------------
__global__ void k_embed(const float* __restrict__ src, const float* __restrict__ in_w,
                        const float* __restrict__ in_b, float* __restrict__ X0){
  int idx = blockIdx.x*256 + threadIdx.x;
  if (idx >= kB*kS*kD) return;
  int j = idx % kD; int bs = idx / kD; int s = bs % kS;
  float v = (src[bs] * in_w[j] + in_b[j]) * 6.928203230275509f;
  X0[idx] = v + pe_fast(s, j);
}

// ---------------- K2: encoder QKV projection, fp16 x + dot2 ----------------
__global__ void __launch_bounds__(256) k_qkv(const float* __restrict__ X,
    const float* __restrict__ wq, const float* __restrict__ bq,
    const float* __restrict__ wk, const float* __restrict__ bk,
    const float* __restrict__ wv, const float* __restrict__ bv,
    __half* __restrict__ Q, __half* __restrict__ K, __half* __restrict__ V){
  __shared__ __align__(16) __half W[3*2688];     // col stride 56 halves
  __shared__ __align__(16) float bias[3*kD];
  __shared__ __align__(16) __half2 xt2[32*24];
  int tid = threadIdx.x;
  for (int i=tid;i<3*2304;i+=256){ int m=i/2304, e=i%2304, k=e/48, j=e%48;
    const float* w = (m==0)?wq:((m==1)?wk:wv);
    W[m*2688 + j*56 + k] = __float2half(w[e]); }
  for (int i=tid;i<3*kD;i+=256){ int m=i/kD,e=i%kD;
    const float* w=(m==0)?bq:((m==1)?bk:bv); bias[i]=w[e]; }
  long row0 = (long)blockIdx.x*32;
  const float2* Xp=(const float2*)(X+row0*kD);
  for (int i=tid;i<768;i+=256){ float2 v=Xp[i]; xt2[i]=__floats2half2_rn(v.x,v.y); }
  __syncthreads();
  int r = tid>>3, c0 = tid&7;
  __half2 xr[24];
  #pragma unroll
  for(int u=0;u<24;u++) xr[u]=xt2[r*24+u];
  for (int c=c0; c<3*kD; c+=8){
    int m=c/kD, j=c%kD;
    float acc = bias[m*kD+j] + dot48d(xr, W + m*2688 + j*56);
    __half* o = (m==0)?Q:((m==1)?K:V);
    o[(row0+r)*kD+j]=__float2half(acc);
  }
}

// ---------------- K3: encoder attention — dot2 scores, float2 (pk) PV acc ----------------
__global__ void __launch_bounds__(256) k_attn(const __half* Q, const __half* __restrict__ K,
                       const __half* __restrict__ V, __half* O){
  int b = blockIdx.x / kNH, h = blockIdx.x % kNH;
  __shared__ __align__(16) __half2 Ks2[kS*6];  // 12 KB
  __shared__ __align__(16) float   Vs[kS*kHD]; // 24 KB (fp32: P stays fp32, no overflow)
  int tid = threadIdx.x;
  long base = ((long)b*kS)*kD + h*kHD;
  for (int i=tid;i<kS*6;i+=256){ int r=i/6, c=i%6;
    Ks2[i]=*(const __half2*)&K[base+(long)r*kD+2*c]; }
  for (int i=tid;i<kS*kHD;i+=256){ int r=i/kHD, d=i%kHD;
    Vs[i]=__half2float(V[base+(long)r*kD+d]); }
  const float rs = 0.28867513459481287f;
  int q0 = tid, q1 = tid+256;
  __half2 qa2[6], qb2[6];
  {
    const __half2* qp0=(const __half2*)(Q+base+(long)q0*kD);
    const __half2* qp1=(const __half2*)(Q+base+(long)q1*kD);
    #pragma unroll
    for(int c=0;c<6;c++){ qa2[c]=qp0[c]; qb2[c]=qp1[c]; }
  }
  __syncthreads();
  float2 acc0[6], acc1[6];
  #pragma unroll
  for(int j=0;j<6;j++){ acc0[j]=make_float2(0.f,0.f); acc1[j]=make_float2(0.f,0.f); }
  float l0=0.f, l1=0.f;
  for(int k=0;k<kS;k++){
    const __half2* kp=Ks2+k*6;
    float sA0=0.f,sA1=0.f,sB0=0.f,sB1=0.f;
    #pragma unroll
    for(int c=0;c<3;c++){
      sA0=fdot2(qa2[2*c],kp[2*c],sA0); sA1=fdot2(qa2[2*c+1],kp[2*c+1],sA1);
      sB0=fdot2(qb2[2*c],kp[2*c],sB0); sB1=fdot2(qb2[2*c+1],kp[2*c+1],sB1);
    }
    float p0=__expf((sA0+sA1)*rs), p1=__expf((sB0+sB1)*rs);
    l0+=p0; l1+=p1;
    const float2* vp=(const float2*)(Vs+k*kHD);
    #pragma unroll
    for(int j=0;j<6;j++){
      float2 v=vp[j];
      acc0[j].x=fmaf(p0,v.x,acc0[j].x); acc0[j].y=fmaf(p0,v.y,acc0[j].y);
      acc1[j].x=fmaf(p1,v.x,acc1[j].x); acc1[j].y=fmaf(p1,v.y,acc1[j].y);
    }
  }
  float i0=1.f/l0, i1=1.f/l1;
  #pragma unroll
  for(int j=0;j<6;j++){
    O[base+(long)q0*kD+2*j  ]=__float2half(acc0[j].x*i0);
    O[base+(long)q0*kD+2*j+1]=__float2half(acc0[j].y*i0);
    O[base+(long)q1*kD+2*j  ]=__float2half(acc1[j].x*i1);
    O[base+(long)q1*kD+2*j+1]=__float2half(acc1[j].y*i1);
  }
}

// ---------------- K4: o-proj + residual + LN, dot2 ----------------
__global__ void __launch_bounds__(256) k_oproj_ln(const float* __restrict__ Xres, const __half* __restrict__ O,
      const float* __restrict__ wo, const float* __restrict__ bo,
      const float* __restrict__ g, const float* __restrict__ bb,
      __half* __restrict__ Xout){
  __shared__ __align__(16) __half W[kD*56];
  __shared__ float bsh[kD], gs[kD], bs2[kD];
  __shared__ __align__(16) float res[32*kD];
  __shared__ __align__(16) __half2 ot2[32*24];
  __shared__ float mrow[32], rstd[32];
  int tid=threadIdx.x;
  for(int i=tid;i<kD*kD;i+=256){ int k=i/48, j=i%48; W[j*56+k]=__float2half(wo[i]); }
  if(tid<kD){ bsh[tid]=bo[tid]; gs[tid]=g[tid]; bs2[tid]=bb[tid]; }
  long row0=(long)blockIdx.x*32;
  const __half2* Op=(const __half2*)(O+row0*kD);
  for(int i=tid;i<768;i+=256) ot2[i]=Op[i];
  __syncthreads();
  int r=tid>>3, c0=tid&7;
  __half2 orow[24];
  #pragma unroll
  for(int u=0;u<24;u++) orow[u]=ot2[r*24+u];
  for(int j=c0;j<kD;j+=8){
    float acc=bsh[j]+dot48d(orow, W+j*56);
    res[r*kD+j]=Xres[row0*kD + r*kD + j]+acc;
  }
  __syncthreads();
  if(tid<32){
    float s=0.f, s2=0.f;
    for(int j=0;j<kD;j++){ float v=res[tid*kD+j]; s+=v; s2+=v*v; }
    float m=s*(1.f/kD);
    mrow[tid]=m; rstd[tid]=rsqrtf(s2*(1.f/kD)-m*m+1e-5f);
  }
  __syncthreads();
  for(int i=tid;i<32*kD;i+=256){int r2=i/kD,j=i%kD;
    Xout[row0*kD+i]=__float2half((res[i]-mrow[r2])*rstd[r2]*gs[j]+bs2[j]); }
}

// ---------------- K5: FFN + residual + LN, dot2 ----------------
__global__ void __launch_bounds__(256) k_ffn_ln(const __half* __restrict__ Xin,
   const float* __restrict__ w1, const float* __restrict__ b1,
   const float* __restrict__ w2, const float* __restrict__ b2,
   const float* __restrict__ g, const float* __restrict__ bb,
   float* __restrict__ Xout){
  __shared__ __align__(16) __half W1[kFF*56];
  __shared__ __align__(16) __half W2[kD*136];
  __shared__ float b1s[kFF], b2s[kD], gs[kD], bs2[kD];
  __shared__ __align__(16) __half xt[16*kD];
  __shared__ __align__(16) __half h1h[16*kFF];
  __shared__ __align__(16) float res[16*kD];
  __shared__ float mrow[16], rstd[16];
  int tid=threadIdx.x;
  for(int i=tid;i<kD*kFF;i+=256){ int k=i/128, c=i%128; W1[c*56+k]=__float2half(w1[i]); }
  for(int i=tid;i<kFF*kD;i+=256){ int u=i/48, j=i%48; W2[j*136+u]=__float2half(w2[i]); }
  if(tid<kFF) b1s[tid]=b1[tid];
  if(tid<kD){ b2s[tid]=b2[tid]; gs[tid]=g[tid]; bs2[tid]=bb[tid]; }
  long row0=(long)blockIdx.x*16;
  const __half2* Xp=(const __half2*)(Xin+row0*kD);
  for(int i=tid;i<384;i+=256) ((__half2*)xt)[i]=Xp[i];
  __syncthreads();
  int r=tid>>4, c0=tid&15;
  {
    __half2 xr[24];
    const __half2* xp=(const __half2*)(xt + r*kD);
    #pragma unroll
    for(int u=0;u<24;u++) xr[u]=xp[u];
    for(int c=c0;c<kFF;c+=16){
      float acc=b1s[c]+dot48d(xr, W1+c*56);
      h1h[r*kFF+c]=__float2half(fmaxf(acc,0.f));
    }
  }
  __syncthreads();
  {
    const __half2* hp=(const __half2*)(h1h + r*kFF);
    for(int j=c0;j<kD;j+=16){
      float acc=b2s[j]+dot128d(hp, W2+j*136);
      res[r*kD+j]=__half2float(xt[r*kD+j])+acc;
    }
  }
  __syncthreads();
  if(tid<16){
    float s=0.f, s2=0.f;
    for(int j=0;j<kD;j++){ float v=res[tid*kD+j]; s+=v; s2+=v*v; }
    float m=s*(1.f/kD);
    mrow[tid]=m; rstd[tid]=rsqrtf(s2*(1.f/kD)-m*m+1e-5f);
  }
  __syncthreads();
  for(int i=tid;i<16*kD;i+=256){int r2=i/kD,j=i%kD;
    Xout[row0*kD+i]=(res[i]-mrow[r2])*rstd[r2]*gs[j]+bs2[j]; }
}

// ---------------- K6: cross K/V projection — K row-major [b][s][d], V transposed [b][d][s] ----------------
__global__ void __launch_bounds__(256) k_ckv(const float* __restrict__ M,
    const float* __restrict__ wk, const float* __restrict__ bk,
    const float* __restrict__ wv, const float* __restrict__ bv,
    __half* __restrict__ Kc, __half* __restrict__ Vc){
  __shared__ __align__(16) __half W[2*2688];
  __shared__ float bias[2*kD];
  __shared__ __align__(16) __half2 xt2[32*24];
  int tid=threadIdx.x;
  for(int i=tid;i<2*2304;i+=256){ int m=i/2304, e=i%2304, k=e/48, j=e%48;
    W[m*2688 + j*56 + k] = __float2half((m?wv:wk)[e]); }
  for(int i=tid;i<2*kD;i+=256){ int m=i/kD,e=i%kD; bias[i]=(m?bv:bk)[e]; }
  long row0=(long)blockIdx.x*32;
  const float2* Mp=(const float2*)(M+row0*kD);
  for(int i=tid;i<768;i+=256){ float2 v=Mp[i]; xt2[i]=__floats2half2_rn(v.x,v.y); }
  __syncthreads();
  int r=tid>>3, c0=tid&7;
  __half2 xr[24];
  #pragma unroll
  for(int u=0;u<24;u++) xr[u]=xt2[r*24+u];
  long gr=row0+r; long bb2=gr>>9; long s=gr&511;
  for(int c=c0;c<2*kD;c+=8){
    int m=c/kD, j=c%kD;
    float acc=bias[m*kD+j]+dot48d(xr, W+m*2688+j*56);
    if(m==0) Kc[(bb2*kS+s)*kD + j]=__float2half(acc);     // [b][s][d]
    else     Vc[(bb2*kD+j)*kS + s]=__float2half(acc);     // [b][d][s]
  }
}

// ---------------- K0: decoder weights -> padded FP16, column-major ----------------
// Wh halves: 6 mats 48 cols stride 56: swq@0 swk@2688 swv@5376 swo@8064 cwq@10752
// cwo@13440; w1 128 cols stride 56 @16128; w2 48 cols stride 136 @23296. Tot 29824.
__global__ void k_prep(const float* __restrict__ swq,const float* __restrict__ swk,
                       const float* __restrict__ swv,const float* __restrict__ swo,
                       const float* __restrict__ cwq,const float* __restrict__ cwo,
                       const float* __restrict__ w1,const float* __restrict__ w2,
                       __half* __restrict__ Wh){
  int idx=blockIdx.x*256+threadIdx.x;
  if(idx>=26112) return;
  if(idx<13824){
    int m=idx/2304, e=idx%2304, j=e/48, k=e%48;
    const float* w = (m==0)?swq:((m==1)?swk:((m==2)?swv:((m==3)?swo:((m==4)?cwq:cwo))));
    Wh[m*2688 + j*56 + k] = __float2half(w[k*48+j]);
  } else if(idx<19968){
    int e=idx-13824, c=e/48, k=e%48;
    Wh[16128 + c*56 + k] = __float2half(w1[k*128+c]);
  } else {
    int e=idx-19968, j=e/128, u=e%128;
    Wh[23296 + j*136 + u] = __float2half(w2[u*48+j]);
  }
}

// ---------------- K7: decoder — R15: reg-weights, reg-buffered y, fused A0 ----------------
struct DecP {
  const float *dec_start, *sbq, *sbk, *sbv, *sbo, *ln1g, *ln1b,
              *cbq, *cbo, *ln2g, *ln2b, *fb1, *fb2, *ln3g, *ln3b, *ow, *ob;
};

__global__ void __launch_bounds__(256,1) k_dec(const __half* __restrict__ KT,
    const __half* __restrict__ VT, const __half* __restrict__ Wg, DecP P,
    float* __restrict__ out){
  __shared__ __align__(16) __half Wl[29824];       // fp16 weights, 58.25 KB
  __shared__ __align__(16) float peT[kT*kD];       // PE table, 12 KB
  __shared__ __align__(16) __half KhH[kNH*kT*kHD]; // self-K cache fp16, 6 KB
  __shared__ __align__(16) float  Vh[kNH*kT*kHD];  // self-V cache fp32, 12 KB
  __shared__ __align__(16) __half qSH[kNH*kHD];    // q by head, fp16
  __shared__ __align__(16) __half xvH[kD], soH[kD], h1H[kD], cqH[kD], covH[kD], h2H[kD];
  __shared__ __align__(16) __half f1H[kFF];
  int tid=threadIdx.x, b=blockIdx.x, wave=tid>>6, lane=tid&63;
  const float rs=0.28867513459481287f;

  for(int i=tid;i<29824/8;i+=256) ((float4*)Wl)[i]=((const float4*)Wg)[i];
  for(int i=tid;i<kT*kD;i+=256){ int tt=i/kD, j=i%kD; peT[i]=pe_val(tt,j); }

  // wave0 per-lane constants (wave0 runs every stage except cross-attn)
  float c_sbq=0,c_sbk=0,c_sbv=0, c_bo=0,c_cbq=0,c_cbo=0,c_fb2=0;
  float g1=0,bb1=0,g2=0,bb2=0,g3=0,bb3=0,c_ow=0, c_fb1a=0,c_fb1b=0, c_ds=0;
  if(wave==0){
    if(lane<kD){
      c_ds=P.dec_start[lane];
      c_sbq=P.sbq[lane]; c_sbk=P.sbk[lane]; c_sbv=P.sbv[lane];
      c_bo=P.sbo[lane]; c_cbq=P.cbq[lane]; c_cbo=P.cbo[lane]; c_fb2=P.fb2[lane];
      g1=P.ln1g[lane]; bb1=P.ln1b[lane];
      g2=P.ln2g[lane]; bb2=P.ln2b[lane];
      g3=P.ln3g[lane]; bb3=P.ln3b[lane];
      c_ow=P.ow[lane];
    }
    c_fb1a=P.fb1[lane]; c_fb1b=P.fb1[lane+64];
  }
  float c_ob=P.ob[0];

  // cross-attn K/V resident in registers: head = wave, 4 key-PAIRS per lane
  // Kc layout [b][s][d]; Vc layout [b][d][s] read as half2 pairs along s.
  __half2 Kr2[4][2][6], Vr2[4][kHD];   // 48 + 48 VGPRs
  {
    const __half* Kb = KT + (long)b*kS*kD;
    const __half2* Vb = (const __half2*)VT + (long)b*kD*(kS/2);
    #pragma unroll
    for(int i=0;i<4;i++){
      int sp = lane + 64*i;
      #pragma unroll
      for(int e=0;e<2;e++){
        const __half2* kp=(const __half2*)(Kb + (long)(2*sp+e)*kD + wave*kHD);
        #pragma unroll
        for(int c=0;c<6;c++) Kr2[i][e][c]=kp[c];
      }
      #pragma unroll
      for(int u=0;u<kHD;u++) Vr2[i][u]=Vb[(wave*kHD+u)*(kS/2)+sp];
    }
  }
  __syncthreads();

  // R15: Wo / Wcq / Wco columns in registers (col = lane, clamped)
  __half2 wA3[24], wA4[24], wC0[24];
  {
    int col = (lane<kD)?lane:0;
    const __half2* p3=(const __half2*)(Wl+ 8064+col*56);
    const __half2* p4=(const __half2*)(Wl+10752+col*56);
    const __half2* p0=(const __half2*)(Wl+13440+col*56);
    #pragma unroll
    for(int u=0;u<24;u++){ wA3[u]=p3[u]; wA4[u]=p4[u]; wC0[u]=p0[u]; }
  }

  // peel t=0's A0: wave0 publishes x0
  float xv=0;
  if(wave==0 && lane<kD){ xv=c_ds+peT[lane]; xvH[lane]=__float2half(xv); }
  __syncthreads();

  float h1=0, h2=0, yacc=0;
  for(int t=0;t<kT;t++){
    // ======== A: wave0-only segment (wsync handoffs, no block barriers) ========
    if(wave==0){
      // A1: qkv — 3 independent dots per lane (pipelined)
      if(lane<kD){
        float qv=c_sbq+dot48d((const __half2*)xvH, Wl + 0*2688 + lane*56);
        float kv=c_sbk+dot48d((const __half2*)xvH, Wl + 1*2688 + lane*56);
        float vv=c_sbv+dot48d((const __half2*)xvH, Wl + 2*2688 + lane*56);
        int hh=lane/kHD, dd=lane%kHD;
        qSH[lane]=__float2half(qv);
        KhH[(hh*kT+t)*kHD+dd]=__float2half(kv);
        Vh[(hh*kT+t)*kHD+dd]=vv;
      }
      wsync();
      // A2: self-attn, 4 heads in one wave: lane = head*16 + keygroup
      {
        int hh=lane>>4, g=lane&15;
        __half2 q2[6];
        const __half2* qp=(const __half2*)qSH + hh*6;
        #pragma unroll
        for(int c=0;c<6;c++) q2[c]=qp[c];
        float l=0.f, acc[kHD];
        #pragma unroll
        for(int u=0;u<kHD;u++) acc[u]=0.f;
        #pragma unroll
        for(int kk=0;kk<4;kk++){
          int key=g+16*kk;
          if(key<=t){
            const __half2* kp=(const __half2*)KhH + (hh*kT+key)*6;
            float a0=0.f,a1=0.f;
            a0=fdot2(q2[0],kp[0],a0); a1=fdot2(q2[1],kp[1],a1);
            a0=fdot2(q2[2],kp[2],a0); a1=fdot2(q2[3],kp[3],a1);
            a0=fdot2(q2[4],kp[4],a0); a1=fdot2(q2[5],kp[5],a1);
            float p=__expf((a0+a1)*rs);
            l+=p;
            const float4* vp=(const float4*)(Vh+(hh*kT+key)*kHD);
            float4 v0=vp[0], v1=vp[1], v2=vp[2];
            float vr[kHD]={v0.x,v0.y,v0.z,v0.w,v1.x,v1.y,v1.z,v1.w,v2.x,v2.y,v2.z,v2.w};
            #pragma unroll
            for(int u=0;u<kHD;u++) acc[u]+=p*vr[u];
          }
        }
        l=rowsum16(l);
        #pragma unroll
        for(int u=0;u<kHD;u++) acc[u]=rowsum16(acc[u]);
        if(g==15){
          float inv=1.f/l;
          #pragma unroll
          for(int u=0;u<6;u++)
            ((__half2*)soH)[hh*6+u]=__floats2half2_rn(acc[2*u]*inv, acc[2*u+1]*inv);
        }
      }
      wsync();
      // A3: self o-proj (reg weights) + residual + LN1
      {
        float rr=0.f;
        if(lane<kD)
          rr=xv+c_bo+dot48r((const __half2*)soH, wA3);
        float s1=wsum(rr), s2=wsum(rr*rr);
        float mean=s1*(1.f/48.f);
        float rstd=rsqrtf(s2*(1.f/48.f)-mean*mean+1e-5f);
        h1=0;
        if(lane<kD){ h1=(rr-mean)*rstd*g1+bb1; h1H[lane]=__float2half(h1); }
      }
      wsync();
      // A4: cross-q (reg weights)
      if(lane<kD)
        cqH[lane]=__float2half(c_cbq+dot48r((const __half2*)h1H, wA4));
    }
    __syncthreads();                                   // B1: cqH -> all waves
    // ======== X: cross-attn on all 4 waves (head = wave); fp32 P, no max-sub ========
    {
      __half2 q2[6];
      #pragma unroll
      for(int c=0;c<6;c++) q2[c]=((const __half2*)cqH)[wave*6+c];
      float s[8];
      #pragma unroll
      for(int i=0;i<4;i++){
        #pragma unroll
        for(int e=0;e<2;e++){
          float a0=0.f,a1=0.f;
          const __half2* kp=Kr2[i][e];
          a0=fdot2(q2[0],kp[0],a0); a1=fdot2(q2[1],kp[1],a1);
          a0=fdot2(q2[2],kp[2],a0); a1=fdot2(q2[3],kp[3],a1);
          a0=fdot2(q2[4],kp[4],a0); a1=fdot2(q2[5],kp[5],a1);
          s[2*i+e]=(a0+a1)*rs;
        }
      }
      float p32[8], l=0.f;
      #pragma unroll
      for(int j=0;j<8;j++){ p32[j]=__expf(s[j]); l+=p32[j]; }
      l=wsum(l);
      float inv=1.f/l;
      __half2 ph[4];
      #pragma unroll
      for(int i=0;i<4;i++) ph[i]=__floats2half2_rn(p32[2*i]*inv, p32[2*i+1]*inv);
      float acc[kHD];
      #pragma unroll
      for(int u=0;u<kHD;u++) acc[u]=0.f;
      #pragma unroll
      for(int i=0;i<4;i++){
        #pragma unroll
        for(int u=0;u<kHD;u++) acc[u]=fdot2(ph[i],Vr2[i][u],acc[u]);
      }
      #pragma unroll
      for(int u=0;u<kHD;u++) acc[u]=wsum(acc[u]);
      if(lane==0){
        #pragma unroll
        for(int u=0;u<6;u++)
          ((__half2*)covH)[wave*6+u]=__floats2half2_rn(acc[2*u], acc[2*u+1]);
      }
    }
    __syncthreads();                                   // B2: covH -> wave0
    // ======== C: wave0-only segment ========
    if(wave==0){
      // C0: cross o-proj (reg weights) + residual + LN2
      {
        float rr=0.f;
        if(lane<kD)
          rr=h1+c_cbo+dot48r((const __half2*)covH, wC0);
        float s1=wsum(rr), s2=wsum(rr*rr);
        float mean=s1*(1.f/48.f);
        float rstd=rsqrtf(s2*(1.f/48.f)-mean*mean+1e-5f);
        h2=0;
        if(lane<kD){ h2=(rr-mean)*rstd*g2+bb2; h2H[lane]=__float2half(h2); }
      }
      wsync();
      // C1: FFN1 — 2 cols per lane (pipelined)
      {
        float a=c_fb1a+dot48d((const __half2*)h2H, Wl+16128+lane*56);
        float bcol=c_fb1b+dot48d((const __half2*)h2H, Wl+16128+(lane+64)*56);
        f1H[lane]=__float2half(fmaxf(a,0.f));
        f1H[lane+64]=__float2half(fmaxf(bcol,0.f));
      }
      wsync();
      // C2: FFN2 + residual + LN3; fused next-x publish; y into reg buffer
      {
        float rr=0.f;
        if(lane<kD)
          rr=h2+c_fb2+dot128d((const __half2*)f1H, Wl+23296+lane*136);
        float s1=wsum(rr), s2=wsum(rr*rr);
        float mean=s1*(1.f/48.f);
        float rstd=rsqrtf(s2*(1.f/48.f)-mean*mean+1e-5f);
        float cv=0.f;
        if(lane<kD) cv=(rr-mean)*rstd*g3+bb3;
        // publish x_{t+1} FIRST (hides under the y-reduction)
        if(lane<kD && t+1<kT){ xv=cv+peT[(t+1)*kD+lane]; xvH[lane]=__float2half(xv); }
        wsync();
        float y=wsum(cv*c_ow);
        if(lane==t) yacc=y;
      }
    }
  }
  if(wave==0) out[(long)b*kT+lane]=yacc+c_ob;
}

extern "C" void kernel_launch(void* const* d_in, const int* in_sizes, int n_in,
                              void* d_out, int out_size, void* d_ws, size_t ws_size,
                              hipStream_t stream){
  // ws: Wh fp16 (reserve 65536 B), A fp32 NB, H1/H2/H3 fp16 NB each (~31.5 MiB).
  float* ws = (float*)d_ws;
  __half* Wh = (__half*)ws;
  const size_t NB = (size_t)kB*kS*kD;     // 3,145,728
  float*  A  = ws + 16384;
  __half* H1 = (__half*)(A + NB);
  __half* H2 = H1 + NB;
  __half* H3 = H2 + NB;

  k_embed<<<(kB*kS*kD+255)/256,256,0,stream>>>((const float*)d_in[0],(const float*)d_in[1],(const float*)d_in[2],A);
  k_qkv  <<<(kB*kS)/32,256,0,stream>>>(A,(const float*)d_in[4],(const float*)d_in[5],(const float*)d_in[6],
                                       (const float*)d_in[7],(const float*)d_in[8],(const float*)d_in[9],H1,H2,H3);
  k_attn <<<kB*kNH,256,0,stream>>>(H1,H2,H3,H1);
  k_oproj_ln<<<(kB*kS)/32,256,0,stream>>>(A,H1,(const float*)d_in[10],(const float*)d_in[11],
                                          (const float*)d_in[12],(const float*)d_in[13],H2);
  k_ffn_ln  <<<(kB*kS)/16,256,0,stream>>>(H2,(const float*)d_in[14],(const float*)d_in[15],(const float*)d_in[16],
                                          (const float*)d_in[17],(const float*)d_in[18],(const float*)d_in[19],A);
  k_ckv     <<<(kB*kS)/32,256,0,stream>>>(A,(const float*)d_in[32],(const float*)d_in[33],
                                          (const float*)d_in[34],(const float*)d_in[35],H1,H3);
  k_prep    <<<(26112+255)/256,256,0,stream>>>((const float*)d_in[20],(const float*)d_in[22],(const float*)d_in[24],
                                               (const float*)d_in[26],(const float*)d_in[30],(const float*)d_in[36],
                                               (const float*)d_in[40],(const float*)d_in[42],Wh);
  DecP P;
  P.dec_start=(const float*)d_in[3];
  P.sbq=(const float*)d_in[21]; P.sbk=(const float*)d_in[23]; P.sbv=(const float*)d_in[25]; P.sbo=(const float*)d_in[27];
  P.ln1g=(const float*)d_in[28]; P.ln1b=(const float*)d_in[29];
  P.cbq=(const float*)d_in[31]; P.cbo=(const float*)d_in[37];
  P.ln2g=(const float*)d_in[38]; P.ln2b=(const float*)d_in[39];
  P.fb1=(const float*)d_in[41]; P.fb2=(const float*)d_in[43];
  P.ln3g=(const float*)d_in[44]; P.ln3b=(const float*)d_in[45];
  P.ow=(const float*)d_in[46]; P.ob=(const float*)d_in[47];
  k_dec<<<kB,256,0,stream>>>(H1,H3,Wh,P,(float*)d_out);
}

// Round 7
// 576.655 us; speedup vs baseline: 1.0556x; 1.0556x over previous
//
#include <hip/hip_runtime.h>
#include <hip/hip_bf16.h>
#include <hip/hip_fp16.h>

// Inputs/outputs are FP32 (verified R3/R6).
// R10 lesson: KV-in-regs OR weights-in-regs — never both (VGPR cap -> compiler demotes).
// R11 lesson: redundant all-wave broadcast stages LOSE (4x LDS traffic > 3 barriers).
// R12 lesson: v_dot2 + fp16 LDS cut k_dec 450->335; VALUBusy 8% -> latency-bound.
// R13 lesson: dual-chain/block doubles per-CU throughput but wall time is set by
//   per-step CRITICAL PATH. R14 lesson: mega-wave0 segments + 2 barriers/step
//   cut 316->236us; implied clock ~1.1GHz at this occupancy.
// R15 lesson: Wo/Wcq/Wco "in registers" regressed (VGPR_Count 136 proves the
//   compiler demoted the arrays; scratch reload > LDS gather). REVERTED here.
// R16: revert (a); keep reg-buffered y + fused A0 + no-wmax cross-attn + encoder
//   float2 PV; A1 reads x into regs once (reused across 3 dots); k_embed fused
//   into k_qkv (one fewer launch + one fewer 12.6MB pass).

constexpr int kB  = 128;
constexpr int kS  = 512;
constexpr int kT  = 64;
constexpr int kD  = 48;
constexpr int kFF = 128;
constexpr int kNH = 4;
constexpr int kHD = 12;

__device__ __forceinline__ void wsync(){
  __builtin_amdgcn_wave_barrier();
  asm volatile("" ::: "memory");
}

// ---- DPP wave64 reductions (VALU-speed) ----
template<int CTRL,int RM,int BM,bool BC>
__device__ __forceinline__ float dppmov(float x, float old){
  return __builtin_bit_cast(float, __builtin_amdgcn_update_dpp(
      __builtin_bit_cast(int, old), __builtin_bit_cast(int, x), CTRL, RM, BM, BC));
}
// sum across 64 lanes, result uniform in all lanes
__device__ __forceinline__ float wsum(float x){
  x += dppmov<0x111,0xf,0xf,true>(x, 0.f);   // row_shr:1
  x += dppmov<0x112,0xf,0xf,true>(x, 0.f);   // row_shr:2
  x += dppmov<0x114,0xf,0xf,true>(x, 0.f);   // row_shr:4
  x += dppmov<0x118,0xf,0xf,true>(x, 0.f);   // row_shr:8
  x += dppmov<0x142,0xa,0xf,true>(x, 0.f);   // row_bcast:15 -> rows 1,3
  x += dppmov<0x143,0xc,0xf,true>(x, 0.f);   // row_bcast:31 -> rows 2,3
  return __builtin_bit_cast(float, __builtin_amdgcn_readlane(__builtin_bit_cast(int, x), 63));
}
// sum within each 16-lane row; result valid at lane 15 of each row
__device__ __forceinline__ float rowsum16(float x){
  x += dppmov<0x111,0xf,0xf,true>(x, 0.f);
  x += dppmov<0x112,0xf,0xf,true>(x, 0.f);
  x += dppmov<0x114,0xf,0xf,true>(x, 0.f);
  x += dppmov<0x118,0xf,0xf,true>(x, 0.f);
  return x;
}

// pe[p, 2i] = sin(p * exp(-2i*ln(10000)/48)), pe[p, 2i+1] = cos(...)
__device__ __forceinline__ float pe_val(int p, int j){   // precise (table init)
  int i = j >> 1;
  float f = expf(-0.19188209108283716f * (float)(2*i));
  float a = (float)p * f;
  return (j & 1) ? cosf(a) : sinf(a);
}
__device__ __forceinline__ float pe_fast(int p, int j){  // encoder embed
  int i = j >> 1;
  float f = __expf(-0.19188209108283716f * (float)(2*i));
  float a = (float)p * f;
  return (j & 1) ? __cosf(a) : __sinf(a);
}

// ---- packed fp16 dot: d = a.x*b.x + a.y*b.y + c (v_dot2_f32_f16) ----
typedef _Float16 h2v __attribute__((ext_vector_type(2)));
union H2U { __half2 h; h2v v; };
__device__ __forceinline__ float fdot2(__half2 a, __half2 b, float c){
#if __has_builtin(__builtin_amdgcn_fdot2)
  H2U ua, ub; ua.h=a; ub.h=b;
  return __builtin_amdgcn_fdot2(ua.v, ub.v, c, false);
#else
  float2 fa=__half22float2(a), fb=__half22float2(b);
  return fmaf(fa.y, fb.y, fmaf(fa.x, fb.x, c));
#endif
}

// 48-dot, x (LDS or reg array) vs w (LDS), 4 accumulator chains
__device__ __forceinline__ float dot48d(const __half2* x, const __half* w){
  const __half2* w2=(const __half2*)w;
  float a0=0.f,a1=0.f,a2=0.f,a3=0.f;
  #pragma unroll
  for(int c=0;c<6;c++){
    a0=fdot2(x[4*c+0],w2[4*c+0],a0);
    a1=fdot2(x[4*c+1],w2[4*c+1],a1);
    a2=fdot2(x[4*c+2],w2[4*c+2],a2);
    a3=fdot2(x[4*c+3],w2[4*c+3],a3);
  }
  return (a0+a1)+(a2+a3);
}
// 128-dot, 8 accumulator chains
__device__ __forceinline__ float dot128d(const __half2* x, const __half* w){
  const __half2* w2=(const __half2*)w;
  float a0=0.f,a1=0.f,a2=0.f,a3=0.f,a4=0.f,a5=0.f,a6=0.f,a7=0.f;
  #pragma unroll
  for(int c=0;c<8;c++){
    a0=fdot2(x[8*c+0],w2[8*c+0],a0);
    a1=fdot2(x[8*c+1],w2[8*c+1],a1);
    a2=fdot2(x[8*c+2],w2[8*c+2],a2);
    a3=fdot2(x[8*c+3],w2[8*c+3],a3);
    a4=fdot2(x[8*c+4],w2[8*c+4],a4);
    a5=fdot2(x[8*c+5],w2[8*c+5],a5);
    a6=fdot2(x[8*c+6],w2[8*c+6],a6);
    a7=fdot2(x[8*c+7],w2[8*c+7],a7);
  }
  return ((a0+a1)+(a2+a3))+((a4+a5)+(a6+a7));
}

// ---------------- K2: FUSED embed + encoder QKV projection ----------------
__global__ void __launch_bounds__(256) k_qkv(const float* __restrict__ src,
    const float* __restrict__ in_w, const float* __restrict__ in_b,
    float* __restrict__ X0,
    const float* __restrict__ wq, const float* __restrict__ bq,
    const float* __restrict__ wk, const float* __restrict__ bk,
    const float* __restrict__ wv, const float* __restrict__ bv,
    __half* __restrict__ Q, __half* __restrict__ K, __half* __restrict__ V){
  __shared__ __align__(16) __half W[3*2688];     // col stride 56 halves
  __shared__ __align__(16) float bias[3*kD];
  __shared__ __align__(16) __half2 xt2[32*24];
  int tid = threadIdx.x;
  for (int i=tid;i<3*2304;i+=256){ int m=i/2304, e=i%2304, k=e/48, j=e%48;
    const float* w = (m==0)?wq:((m==1)?wk:wv);
    W[m*2688 + j*56 + k] = __float2half(w[e]); }
  for (int i=tid;i<3*kD;i+=256){ int m=i/kD,e=i%kD;
    const float* w=(m==0)?bq:((m==1)?bk:bv); bias[i]=w[e]; }
  long row0 = (long)blockIdx.x*32;
  const float sc = 6.928203230275509f;
  // fused embed: x = (src*in_w+in_b)*sqrt(d) + pe; fp32 -> X0, fp16 -> LDS
  for (int i=tid;i<768;i+=256){
    int r=i/24, c=i%24;
    long gr=row0+r; int s=(int)(gr&511);
    float sv=src[gr];
    float va=(sv*in_w[2*c  ]+in_b[2*c  ])*sc + pe_fast(s,2*c  );
    float vb=(sv*in_w[2*c+1]+in_b[2*c+1])*sc + pe_fast(s,2*c+1);
    ((float2*)X0)[row0*24 + i]=make_float2(va,vb);
    xt2[i]=__floats2half2_rn(va,vb);
  }
  __syncthreads();
  int r = tid>>3, c0 = tid&7;
  __half2 xr[24];
  #pragma unroll
  for(int u=0;u<24;u++) xr[u]=xt2[r*24+u];
  for (int c=c0; c<3*kD; c+=8){
    int m=c/kD, j=c%kD;
    float acc = bias[m*kD+j] + dot48d(xr, W + m*2688 + j*56);
    __half* o = (m==0)?Q:((m==1)?K:V);
    o[(row0+r)*kD+j]=__float2half(acc);
  }
}

// ---------------- K3: encoder attention — dot2 scores, float2 (pk) PV acc ----------------
__global__ void __launch_bounds__(256) k_attn(const __half* Q, const __half* __restrict__ K,
                       const __half* __restrict__ V, __half* O){
  int b = blockIdx.x / kNH, h = blockIdx.x % kNH;
  __shared__ __align__(16) __half2 Ks2[kS*6];  // 12 KB
  __shared__ __align__(16) float   Vs[kS*kHD]; // 24 KB (fp32: P stays fp32, no overflow)
  int tid = threadIdx.x;
  long base = ((long)b*kS)*kD + h*kHD;
  for (int i=tid;i<kS*6;i+=256){ int r=i/6, c=i%6;
    Ks2[i]=*(const __half2*)&K[base+(long)r*kD+2*c]; }
  for (int i=tid;i<kS*kHD;i+=256){ int r=i/kHD, d=i%kHD;
    Vs[i]=__half2float(V[base+(long)r*kD+d]); }
  const float rs = 0.28867513459481287f;
  int q0 = tid, q1 = tid+256;
  __half2 qa2[6], qb2[6];
  {
    const __half2* qp0=(const __half2*)(Q+base+(long)q0*kD);
    const __half2* qp1=(const __half2*)(Q+base+(long)q1*kD);
    #pragma unroll
    for(int c=0;c<6;c++){ qa2[c]=qp0[c]; qb2[c]=qp1[c]; }
  }
  __syncthreads();
  float2 acc0[6], acc1[6];
  #pragma unroll
  for(int j=0;j<6;j++){ acc0[j]=make_float2(0.f,0.f); acc1[j]=make_float2(0.f,0.f); }
  float l0=0.f, l1=0.f;
  for(int k=0;k<kS;k++){
    const __half2* kp=Ks2+k*6;
    float sA0=0.f,sA1=0.f,sB0=0.f,sB1=0.f;
    #pragma unroll
    for(int c=0;c<3;c++){
      sA0=fdot2(qa2[2*c],kp[2*c],sA0); sA1=fdot2(qa2[2*c+1],kp[2*c+1],sA1);
      sB0=fdot2(qb2[2*c],kp[2*c],sB0); sB1=fdot2(qb2[2*c+1],kp[2*c+1],sB1);
    }
    float p0=__expf((sA0+sA1)*rs), p1=__expf((sB0+sB1)*rs);
    l0+=p0; l1+=p1;
    const float2* vp=(const float2*)(Vs+k*kHD);
    #pragma unroll
    for(int j=0;j<6;j++){
      float2 v=vp[j];
      acc0[j].x=fmaf(p0,v.x,acc0[j].x); acc0[j].y=fmaf(p0,v.y,acc0[j].y);
      acc1[j].x=fmaf(p1,v.x,acc1[j].x); acc1[j].y=fmaf(p1,v.y,acc1[j].y);
    }
  }
  float i0=1.f/l0, i1=1.f/l1;
  #pragma unroll
  for(int j=0;j<6;j++){
    O[base+(long)q0*kD+2*j  ]=__float2half(acc0[j].x*i0);
    O[base+(long)q0*kD+2*j+1]=__float2half(acc0[j].y*i0);
    O[base+(long)q1*kD+2*j  ]=__float2half(acc1[j].x*i1);
    O[base+(long)q1*kD+2*j+1]=__float2half(acc1[j].y*i1);
  }
}

// ---------------- K4: o-proj + residual + LN, dot2 ----------------
__global__ void __launch_bounds__(256) k_oproj_ln(const float* __restrict__ Xres, const __half* __restrict__ O,
      const float* __restrict__ wo, const float* __restrict__ bo,
      const float* __restrict__ g, const float* __restrict__ bb,
      __half* __restrict__ Xout){
  __shared__ __align__(16) __half W[kD*56];
  __shared__ float bsh[kD], gs[kD], bs2[kD];
  __shared__ __align__(16) float res[32*kD];
  __shared__ __align__(16) __half2 ot2[32*24];
  __shared__ float mrow[32], rstd[32];
  int tid=threadIdx.x;
  for(int i=tid;i<kD*kD;i+=256){ int k=i/48, j=i%48; W[j*56+k]=__float2half(wo[i]); }
  if(tid<kD){ bsh[tid]=bo[tid]; gs[tid]=g[tid]; bs2[tid]=bb[tid]; }
  long row0=(long)blockIdx.x*32;
  const __half2* Op=(const __half2*)(O+row0*kD);
  for(int i=tid;i<768;i+=256) ot2[i]=Op[i];
  __syncthreads();
  int r=tid>>3, c0=tid&7;
  __half2 orow[24];
  #pragma unroll
  for(int u=0;u<24;u++) orow[u]=ot2[r*24+u];
  for(int j=c0;j<kD;j+=8){
    float acc=bsh[j]+dot48d(orow, W+j*56);
    res[r*kD+j]=Xres[row0*kD + r*kD + j]+acc;
  }
  __syncthreads();
  if(tid<32){
    float s=0.f, s2=0.f;
    for(int j=0;j<kD;j++){ float v=res[tid*kD+j]; s+=v; s2+=v*v; }
    float m=s*(1.f/kD);
    mrow[tid]=m; rstd[tid]=rsqrtf(s2*(1.f/kD)-m*m+1e-5f);
  }
  __syncthreads();
  for(int i=tid;i<32*kD;i+=256){int r2=i/kD,j=i%kD;
    Xout[row0*kD+i]=__float2half((res[i]-mrow[r2])*rstd[r2]*gs[j]+bs2[j]); }
}

// ---------------- K5: FFN + residual + LN, dot2 ----------------
__global__ void __launch_bounds__(256) k_ffn_ln(const __half* __restrict__ Xin,
   const float* __restrict__ w1, const float* __restrict__ b1,
   const float* __restrict__ w2, const float* __restrict__ b2,
   const float* __restrict__ g, const float* __restrict__ bb,
   float* __restrict__ Xout){
  __shared__ __align__(16) __half W1[kFF*56];
  __shared__ __align__(16) __half W2[kD*136];
  __shared__ float b1s[kFF], b2s[kD], gs[kD], bs2[kD];
  __shared__ __align__(16) __half xt[16*kD];
  __shared__ __align__(16) __half h1h[16*kFF];
  __shared__ __align__(16) float res[16*kD];
  __shared__ float mrow[16], rstd[16];
  int tid=threadIdx.x;
  for(int i=tid;i<kD*kFF;i+=256){ int k=i/128, c=i%128; W1[c*56+k]=__float2half(w1[i]); }
  for(int i=tid;i<kFF*kD;i+=256){ int u=i/48, j=i%48; W2[j*136+u]=__float2half(w2[i]); }
  if(tid<kFF) b1s[tid]=b1[tid];
  if(tid<kD){ b2s[tid]=b2[tid]; gs[tid]=g[tid]; bs2[tid]=bb[tid]; }
  long row0=(long)blockIdx.x*16;
  const __half2* Xp=(const __half2*)(Xin+row0*kD);
  for(int i=tid;i<384;i+=256) ((__half2*)xt)[i]=Xp[i];
  __syncthreads();
  int r=tid>>4, c0=tid&15;
  {
    __half2 xr[24];
    const __half2* xp=(const __half2*)(xt + r*kD);
    #pragma unroll
    for(int u=0;u<24;u++) xr[u]=xp[u];
    for(int c=c0;c<kFF;c+=16){
      float acc=b1s[c]+dot48d(xr, W1+c*56);
      h1h[r*kFF+c]=__float2half(fmaxf(acc,0.f));
    }
  }
  __syncthreads();
  {
    const __half2* hp=(const __half2*)(h1h + r*kFF);
    for(int j=c0;j<kD;j+=16){
      float acc=b2s[j]+dot128d(hp, W2+j*136);
      res[r*kD+j]=__half2float(xt[r*kD+j])+acc;
    }
  }
  __syncthreads();
  if(tid<16){
    float s=0.f, s2=0.f;
    for(int j=0;j<kD;j++){ float v=res[tid*kD+j]; s+=v; s2+=v*v; }
    float m=s*(1.f/kD);
    mrow[tid]=m; rstd[tid]=rsqrtf(s2*(1.f/kD)-m*m+1e-5f);
  }
  __syncthreads();
  for(int i=tid;i<16*kD;i+=256){int r2=i/kD,j=i%kD;
    Xout[row0*kD+i]=(res[i]-mrow[r2])*rstd[r2]*gs[j]+bs2[j]; }
}

// ---------------- K6: cross K/V projection — K row-major [b][s][d], V transposed [b][d][s] ----------------
__global__ void __launch_bounds__(256) k_ckv(const float* __restrict__ M,
    const float* __restrict__ wk, const float* __restrict__ bk,
    const float* __restrict__ wv, const float* __restrict__ bv,
    __half* __restrict__ Kc, __half* __restrict__ Vc){
  __shared__ __align__(16) __half W[2*2688];
  __shared__ float bias[2*kD];
  __shared__ __align__(16) __half2 xt2[32*24];
  int tid=threadIdx.x;
  for(int i=tid;i<2*2304;i+=256){ int m=i/2304, e=i%2304, k=e/48, j=e%48;
    W[m*2688 + j*56 + k] = __float2half((m?wv:wk)[e]); }
  for(int i=tid;i<2*kD;i+=256){ int m=i/kD,e=i%kD; bias[i]=(m?bv:bk)[e]; }
  long row0=(long)blockIdx.x*32;
  const float2* Mp=(const float2*)(M+row0*kD);
  for(int i=tid;i<768;i+=256){ float2 v=Mp[i]; xt2[i]=__floats2half2_rn(v.x,v.y); }
  __syncthreads();
  int r=tid>>3, c0=tid&7;
  __half2 xr[24];
  #pragma unroll
  for(int u=0;u<24;u++) xr[u]=xt2[r*24+u];
  long gr=row0+r; long bb2=gr>>9; long s=gr&511;
  for(int c=c0;c<2*kD;c+=8){
    int m=c/kD, j=c%kD;
    float acc=bias[m*kD+j]+dot48d(xr, W+m*2688+j*56);
    if(m==0) Kc[(bb2*kS+s)*kD + j]=__float2half(acc);     // [b][s][d]
    else     Vc[(bb2*kD+j)*kS + s]=__float2half(acc);     // [b][d][s]
  }
}

// ---------------- K0: decoder weights -> padded FP16, column-major ----------------
// Wh halves: 6 mats 48 cols stride 56: swq@0 swk@2688 swv@5376 swo@8064 cwq@10752
// cwo@13440; w1 128 cols stride 56 @16128; w2 48 cols stride 136 @23296. Tot 29824.
__global__ void k_prep(const float* __restrict__ swq,const float* __restrict__ swk,
                       const float* __restrict__ swv,const float* __restrict__ swo,
                       const float* __restrict__ cwq,const float* __restrict__ cwo,
                       const float* __restrict__ w1,const float* __restrict__ w2,
                       __half* __restrict__ Wh){
  int idx=blockIdx.x*256+threadIdx.x;
  if(idx>=26112) return;
  if(idx<13824){
    int m=idx/2304, e=idx%2304, j=e/48, k=e%48;
    const float* w = (m==0)?swq:((m==1)?swk:((m==2)?swv:((m==3)?swo:((m==4)?cwq:cwo))));
    Wh[m*2688 + j*56 + k] = __float2half(w[k*48+j]);
  } else if(idx<19968){
    int e=idx-13824, c=e/48, k=e%48;
    Wh[16128 + c*56 + k] = __float2half(w1[k*128+c]);
  } else {
    int e=idx-19968, j=e/128, u=e%128;
    Wh[23296 + j*136 + u] = __float2half(w2[u*48+j]);
  }
}

// ---------------- K7: decoder — R16: R14 schedule + reg-y + fused A0, LDS weights ----------------
struct DecP {
  const float *dec_start, *sbq, *sbk, *sbv, *sbo, *ln1g, *ln1b,
              *cbq, *cbo, *ln2g, *ln2b, *fb1, *fb2, *ln3g, *ln3b, *ow, *ob;
};

__global__ void __launch_bounds__(256,1) k_dec(const __half* __restrict__ KT,
    const __half* __restrict__ VT, const __half* __restrict__ Wg, DecP P,
    float* __restrict__ out){
  __shared__ __align__(16) __half Wl[29824];       // fp16 weights, 58.25 KB
  __shared__ __align__(16) float peT[kT*kD];       // PE table, 12 KB
  __shared__ __align__(16) __half KhH[kNH*kT*kHD]; // self-K cache fp16, 6 KB
  __shared__ __align__(16) float  Vh[kNH*kT*kHD];  // self-V cache fp32, 12 KB
  __shared__ __align__(16) __half qSH[kNH*kHD];    // q by head, fp16
  __shared__ __align__(16) __half xvH[kD], soH[kD], h1H[kD], cqH[kD], covH[kD], h2H[kD];
  __shared__ __align__(16) __half f1H[kFF];
  int tid=threadIdx.x, b=blockIdx.x, wave=tid>>6, lane=tid&63;
  const float rs=0.28867513459481287f;

  for(int i=tid;i<29824/8;i+=256) ((float4*)Wl)[i]=((const float4*)Wg)[i];
  for(int i=tid;i<kT*kD;i+=256){ int tt=i/kD, j=i%kD; peT[i]=pe_val(tt,j); }

  // wave0 per-lane constants (wave0 runs every stage except cross-attn)
  float c_sbq=0,c_sbk=0,c_sbv=0, c_bo=0,c_cbq=0,c_cbo=0,c_fb2=0;
  float g1=0,bb1=0,g2=0,bb2=0,g3=0,bb3=0,c_ow=0, c_fb1a=0,c_fb1b=0, c_ds=0;
  if(wave==0){
    if(lane<kD){
      c_ds=P.dec_start[lane];
      c_sbq=P.sbq[lane]; c_sbk=P.sbk[lane]; c_sbv=P.sbv[lane];
      c_bo=P.sbo[lane]; c_cbq=P.cbq[lane]; c_cbo=P.cbo[lane]; c_fb2=P.fb2[lane];
      g1=P.ln1g[lane]; bb1=P.ln1b[lane];
      g2=P.ln2g[lane]; bb2=P.ln2b[lane];
      g3=P.ln3g[lane]; bb3=P.ln3b[lane];
      c_ow=P.ow[lane];
    }
    c_fb1a=P.fb1[lane]; c_fb1b=P.fb1[lane+64];
  }
  float c_ob=P.ob[0];

  // cross-attn K/V resident in registers: head = wave, 4 key-PAIRS per lane
  // Kc layout [b][s][d]; Vc layout [b][d][s] read as half2 pairs along s.
  __half2 Kr2[4][2][6], Vr2[4][kHD];   // 48 + 48 VGPRs
  {
    const __half* Kb = KT + (long)b*kS*kD;
    const __half2* Vb = (const __half2*)VT + (long)b*kD*(kS/2);
    #pragma unroll
    for(int i=0;i<4;i++){
      int sp = lane + 64*i;
      #pragma unroll
      for(int e=0;e<2;e++){
        const __half2* kp=(const __half2*)(Kb + (long)(2*sp+e)*kD + wave*kHD);
        #pragma unroll
        for(int c=0;c<6;c++) Kr2[i][e][c]=kp[c];
      }
      #pragma unroll
      for(int u=0;u<kHD;u++) Vr2[i][u]=Vb[(wave*kHD+u)*(kS/2)+sp];
    }
  }
  __syncthreads();

  // peel t=0's A0: wave0 publishes x0
  float xv=0;
  if(wave==0 && lane<kD){ xv=c_ds+peT[lane]; xvH[lane]=__float2half(xv); }
  __syncthreads();

  float h1=0, h2=0, yacc=0;
  for(int t=0;t<kT;t++){
    // ======== A: wave0-only segment (wsync handoffs, no block barriers) ========
    if(wave==0){
      // A1: qkv — x loaded into regs ONCE, reused across 3 dots
      if(lane<kD){
        __half2 xr[24];
        const __half2* xp=(const __half2*)xvH;
        #pragma unroll
        for(int u=0;u<24;u++) xr[u]=xp[u];
        float qv=c_sbq+dot48d(xr, Wl + 0*2688 + lane*56);
        float kv=c_sbk+dot48d(xr, Wl + 1*2688 + lane*56);
        float vv=c_sbv+dot48d(xr, Wl + 2*2688 + lane*56);
        int hh=lane/kHD, dd=lane%kHD;
        qSH[lane]=__float2half(qv);
        KhH[(hh*kT+t)*kHD+dd]=__float2half(kv);
        Vh[(hh*kT+t)*kHD+dd]=vv;
      }
      wsync();
      // A2: self-attn, 4 heads in one wave: lane = head*16 + keygroup
      {
        int hh=lane>>4, g=lane&15;
        __half2 q2[6];
        const __half2* qp=(const __half2*)qSH + hh*6;
        #pragma unroll
        for(int c=0;c<6;c++) q2[c]=qp[c];
        float l=0.f, acc[kHD];
        #pragma unroll
        for(int u=0;u<kHD;u++) acc[u]=0.f;
        #pragma unroll
        for(int kk=0;kk<4;kk++){
          int key=g+16*kk;
          if(key<=t){
            const __half2* kp=(const __half2*)KhH + (hh*kT+key)*6;
            float a0=0.f,a1=0.f;
            a0=fdot2(q2[0],kp[0],a0); a1=fdot2(q2[1],kp[1],a1);
            a0=fdot2(q2[2],kp[2],a0); a1=fdot2(q2[3],kp[3],a1);
            a0=fdot2(q2[4],kp[4],a0); a1=fdot2(q2[5],kp[5],a1);
            float p=__expf((a0+a1)*rs);
            l+=p;
            const float4* vp=(const float4*)(Vh+(hh*kT+key)*kHD);
            float4 v0=vp[0], v1=vp[1], v2=vp[2];
            float vr[kHD]={v0.x,v0.y,v0.z,v0.w,v1.x,v1.y,v1.z,v1.w,v2.x,v2.y,v2.z,v2.w};
            #pragma unroll
            for(int u=0;u<kHD;u++) acc[u]+=p*vr[u];
          }
        }
        l=rowsum16(l);
        #pragma unroll
        for(int u=0;u<kHD;u++) acc[u]=rowsum16(acc[u]);
        if(g==15){
          float inv=1.f/l;
          #pragma unroll
          for(int u=0;u<6;u++)
            ((__half2*)soH)[hh*6+u]=__floats2half2_rn(acc[2*u]*inv, acc[2*u+1]*inv);
        }
      }
      wsync();
      // A3: self o-proj + residual + LN1 (weights from LDS — R15 reg version regressed)
      {
        float rr=0.f;
        if(lane<kD)
          rr=xv+c_bo+dot48d((const __half2*)soH, Wl+8064+lane*56);
        float s1=wsum(rr), s2=wsum(rr*rr);
        float mean=s1*(1.f/48.f);
        float rstd=rsqrtf(s2*(1.f/48.f)-mean*mean+1e-5f);
        h1=0;
        if(lane<kD){ h1=(rr-mean)*rstd*g1+bb1; h1H[lane]=__float2half(h1); }
      }
      wsync();
      // A4: cross-q
      if(lane<kD)
        cqH[lane]=__float2half(c_cbq+dot48d((const __half2*)h1H, Wl+10752+lane*56));
    }
    __syncthreads();                                   // B1: cqH -> all waves
    // ======== X: cross-attn on all 4 waves (head = wave); fp32 P, no max-sub ========
    {
      __half2 q2[6];
      #pragma unroll
      for(int c=0;c<6;c++) q2[c]=((const __half2*)cqH)[wave*6+c];
      float s[8];
      #pragma unroll
      for(int i=0;i<4;i++){
        #pragma unroll
        for(int e=0;e<2;e++){
          float a0=0.f,a1=0.f;
          const __half2* kp=Kr2[i][e];
          a0=fdot2(q2[0],kp[0],a0); a1=fdot2(q2[1],kp[1],a1);
          a0=fdot2(q2[2],kp[2],a0); a1=fdot2(q2[3],kp[3],a1);
          a0=fdot2(q2[4],kp[4],a0); a1=fdot2(q2[5],kp[5],a1);
          s[2*i+e]=(a0+a1)*rs;
        }
      }
      float p32[8], l=0.f;
      #pragma unroll
      for(int j=0;j<8;j++){ p32[j]=__expf(s[j]); l+=p32[j]; }
      l=wsum(l);
      float inv=1.f/l;
      __half2 ph[4];
      #pragma unroll
      for(int i=0;i<4;i++) ph[i]=__floats2half2_rn(p32[2*i]*inv, p32[2*i+1]*inv);
      float acc[kHD];
      #pragma unroll
      for(int u=0;u<kHD;u++) acc[u]=0.f;
      #pragma unroll
      for(int i=0;i<4;i++){
        #pragma unroll
        for(int u=0;u<kHD;u++) acc[u]=fdot2(ph[i],Vr2[i][u],acc[u]);
      }
      #pragma unroll
      for(int u=0;u<kHD;u++) acc[u]=wsum(acc[u]);
      if(lane==0){
        #pragma unroll
        for(int u=0;u<6;u++)
          ((__half2*)covH)[wave*6+u]=__floats2half2_rn(acc[2*u], acc[2*u+1]);
      }
    }
    __syncthreads();                                   // B2: covH -> wave0
    // ======== C: wave0-only segment ========
    if(wave==0){
      // C0: cross o-proj + residual + LN2
      {
        float rr=0.f;
        if(lane<kD)
          rr=h1+c_cbo+dot48d((const __half2*)covH, Wl+13440+lane*56);
        float s1=wsum(rr), s2=wsum(rr*rr);
        float mean=s1*(1.f/48.f);
        float rstd=rsqrtf(s2*(1.f/48.f)-mean*mean+1e-5f);
        h2=0;
        if(lane<kD){ h2=(rr-mean)*rstd*g2+bb2; h2H[lane]=__float2half(h2); }
      }
      wsync();
      // C1: FFN1 — 2 cols per lane (pipelined)
      {
        float a=c_fb1a+dot48d((const __half2*)h2H, Wl+16128+lane*56);
        float bcol=c_fb1b+dot48d((const __half2*)h2H, Wl+16128+(lane+64)*56);
        f1H[lane]=__float2half(fmaxf(a,0.f));
        f1H[lane+64]=__float2half(fmaxf(bcol,0.f));
      }
      wsync();
      // C2: FFN2 + residual + LN3; fused next-x publish; y into reg buffer
      {
        float rr=0.f;
        if(lane<kD)
          rr=h2+c_fb2+dot128d((const __half2*)f1H, Wl+23296+lane*136);
        float s1=wsum(rr), s2=wsum(rr*rr);
        float mean=s1*(1.f/48.f);
        float rstd=rsqrtf(s2*(1.f/48.f)-mean*mean+1e-5f);
        float cv=0.f;
        if(lane<kD) cv=(rr-mean)*rstd*g3+bb3;
        // publish x_{t+1} FIRST (hides under the y-reduction)
        if(lane<kD && t+1<kT){ xv=cv+peT[(t+1)*kD+lane]; xvH[lane]=__float2half(xv); }
        wsync();
        float y=wsum(cv*c_ow);
        if(lane==t) yacc=y;
      }
    }
  }
  if(wave==0) out[(long)b*kT+lane]=yacc+c_ob;
}

extern "C" void kernel_launch(void* const* d_in, const int* in_sizes, int n_in,
                              void* d_out, int out_size, void* d_ws, size_t ws_size,
                              hipStream_t stream){
  // ws: Wh fp16 (reserve 65536 B), A fp32 NB, H1/H2/H3 fp16 NB each (~31.5 MiB).
  float* ws = (float*)d_ws;
  __half* Wh = (__half*)ws;
  const size_t NB = (size_t)kB*kS*kD;     // 3,145,728
  float*  A  = ws + 16384;
  __half* H1 = (__half*)(A + NB);
  __half* H2 = H1 + NB;
  __half* H3 = H2 + NB;

  k_qkv  <<<(kB*kS)/32,256,0,stream>>>((const float*)d_in[0],(const float*)d_in[1],(const float*)d_in[2],A,
                                       (const float*)d_in[4],(const float*)d_in[5],(const float*)d_in[6],
                                       (const float*)d_in[7],(const float*)d_in[8],(const float*)d_in[9],H1,H2,H3);
  k_attn <<<kB*kNH,256,0,stream>>>(H1,H2,H3,H1);
  k_oproj_ln<<<(kB*kS)/32,256,0,stream>>>(A,H1,(const float*)d_in[10],(const float*)d_in[11],
                                          (const float*)d_in[12],(const float*)d_in[13],H2);
  k_ffn_ln  <<<(kB*kS)/16,256,0,stream>>>(H2,(const float*)d_in[14],(const float*)d_in[15],(const float*)d_in[16],
                                          (const float*)d_in[17],(const float*)d_in[18],(const float*)d_in[19],A);
  k_ckv     <<<(kB*kS)/32,256,0,stream>>>(A,(const float*)d_in[32],(const float*)d_in[33],
                                          (const float*)d_in[34],(const float*)d_in[35],H1,H3);
  k_prep    <<<(26112+255)/256,256,0,stream>>>((const float*)d_in[20],(const float*)d_in[22],(const float*)d_in[24],
                                               (const float*)d_in[26],(const float*)d_in[30],(const float*)d_in[36],
                                               (const float*)d_in[40],(const float*)d_in[42],Wh);
  DecP P;
  P.dec_start=(const float*)d_in[3];
  P.sbq=(const float*)d_in[21]; P.sbk=(const float*)d_in[23]; P.sbv=(const float*)d_in[25]; P.sbo=(const float*)d_in[27];
  P.ln1g=(const float*)d_in[28]; P.ln1b=(const float*)d_in[29];
  P.cbq=(const float*)d_in[31]; P.cbo=(const float*)d_in[37];
  P.ln2g=(const float*)d_in[38]; P.ln2b=(const float*)d_in[39];
  P.fb1=(const float*)d_in[41]; P.fb2=(const float*)d_in[43];
  P.ln3g=(const float*)d_in[44]; P.ln3b=(const float*)d_in[45];
  P.ow=(const float*)d_in[46]; P.ob=(const float*)d_in[47];
  k_dec<<<kB,256,0,stream>>>(H1,H3,Wh,P,(float*)d_out);
}